// Round 1
// baseline (20629.536 us; speedup 1.0000x reference)
//
#include <hip/hip_runtime.h>
#include <math.h>

// ---------------- dims ----------------
#define B_ 32
#define C_ 3
#define HW_ 224
#define NP_ 14
#define PS_ 16
#define S_ 197        // NP*NP + 1
#define D_ 768
#define NH_ 12
#define DH_ 64
#define L_ 12
#define MLP_ 3072
#define OUT_ 1000

#define BM 64
#define BN 64
#define BK 16

// ---------------- generic batched fp32 GEMM ----------------
// C[z] = act(A[z] @ B[z] + bias[z]) (+ C_old if accum)
// batch offset model: off = (z/div)*sOuter + (z%div)*sInner
__global__ __launch_bounds__(256) void gemm_kernel(
    const float* __restrict__ A, const float* __restrict__ Bm,
    const float* __restrict__ bias, float* __restrict__ C,
    int M, int N, int K, int lda, int ldb, int ldc,
    int transB, int act, int accum,
    int divA, long long sAo, long long sAi,
    int divB, long long sBo, long long sBi,
    int divC, long long sCo, long long sCi,
    int divBias, long long sBiaso, long long sBiasi)
{
    int z = blockIdx.z;
    const float* Ab = A + (long long)(z / divA) * sAo + (long long)(z % divA) * sAi;
    const float* Bb = Bm + (long long)(z / divB) * sBo + (long long)(z % divB) * sBi;
    float* Cb = C + (long long)(z / divC) * sCo + (long long)(z % divC) * sCi;
    const float* biasb = bias ? (bias + (long long)(z / divBias) * sBiaso + (long long)(z % divBias) * sBiasi)
                              : nullptr;

    __shared__ float As[BK][BM + 4];
    __shared__ float Bs[BK][BN + 4];

    int tid = threadIdx.x;
    int tx = tid & 15, ty = tid >> 4;
    int m0 = blockIdx.y * BM, n0 = blockIdx.x * BN;

    float acc[4][4] = {};

    for (int k0 = 0; k0 < K; k0 += BK) {
        // A tile: BM x BK ; thread t loads row=t/4, 4 consecutive k
        {
            int row = tid >> 2;
            int c4 = (tid & 3) * 4;
            int gm = m0 + row;
#pragma unroll
            for (int u = 0; u < 4; ++u) {
                int gk = k0 + c4 + u;
                float v = 0.f;
                if (gm < M && gk < K) v = Ab[(long long)gm * lda + gk];
                As[c4 + u][row] = v;
            }
        }
        if (!transB) {
            // B tile: BK x BN ; thread t loads k-row = t/16, 4 consecutive n
            int row = tid >> 4;
            int c4 = (tid & 15) * 4;
            int gk = k0 + row;
#pragma unroll
            for (int u = 0; u < 4; ++u) {
                int gn = n0 + c4 + u;
                float v = 0.f;
                if (gk < K && gn < N) v = Bb[(long long)gk * ldb + gn];
                Bs[row][c4 + u] = v;
            }
        } else {
            // B is [N,K] row-major ; thread t loads n-row = t/4, 4 consecutive k
            int row = tid >> 2;
            int c4 = (tid & 3) * 4;
            int gn = n0 + row;
#pragma unroll
            for (int u = 0; u < 4; ++u) {
                int gk = k0 + c4 + u;
                float v = 0.f;
                if (gn < N && gk < K) v = Bb[(long long)gn * ldb + gk];
                Bs[c4 + u][row] = v;
            }
        }
        __syncthreads();
#pragma unroll
        for (int kk = 0; kk < BK; ++kk) {
            float a[4], b[4];
#pragma unroll
            for (int i = 0; i < 4; ++i) a[i] = As[kk][ty * 4 + i];
#pragma unroll
            for (int j = 0; j < 4; ++j) b[j] = Bs[kk][tx * 4 + j];
#pragma unroll
            for (int i = 0; i < 4; ++i)
#pragma unroll
                for (int j = 0; j < 4; ++j)
                    acc[i][j] += a[i] * b[j];
        }
        __syncthreads();
    }

#pragma unroll
    for (int i = 0; i < 4; ++i) {
        int gm = m0 + ty * 4 + i;
        if (gm >= M) continue;
#pragma unroll
        for (int j = 0; j < 4; ++j) {
            int gn = n0 + tx * 4 + j;
            if (gn >= N) continue;
            float v = acc[i][j];
            if (biasb) v += biasb[gn];
            if (act == 1) v = 0.5f * v * (1.0f + erff(v * 0.70710678118654752f));
            long long idx = (long long)gm * ldc + gn;
            if (accum) v += Cb[idx];
            Cb[idx] = v;
        }
    }
}

// ---------------- positional embedding ----------------
__global__ void posemb_kernel(float* __restrict__ pos) {
    int idx = blockIdx.x * 256 + threadIdx.x;
    if (idx >= S_ * D_) return;
    int s = idx / D_, d = idx % D_;
    float jj = (float)(d & ~1);
    float freq = powf(10000.0f, jj / (float)D_);
    float arg = (float)s / freq;
    pos[idx] = (d & 1) ? cosf(arg) : sinf(arg);
}

// ---------------- patchify ----------------
__global__ void patchify_kernel(const float* __restrict__ x, float* __restrict__ patches) {
    int idx = blockIdx.x * 256 + threadIdx.x;
    if (idx >= B_ * NP_ * NP_ * 768) return;
    int k = idx % 768;
    int p = (idx / 768) % (NP_ * NP_);
    int n = idx / (768 * NP_ * NP_);
    int c = k >> 8;
    int rem = k & 255;
    int a = rem >> 4;
    int b = rem & 15;
    int i = p / NP_, j = p % NP_;
    patches[idx] = x[(((long long)n * C_ + c) * HW_ + (i * PS_ + a)) * HW_ + (j * PS_ + b)];
}

// ---------------- cls token + pos emb ----------------
__global__ void addpos_kernel(float* __restrict__ tok, const float* __restrict__ pos,
                              const float* __restrict__ cls) {
    int idx = blockIdx.x * 256 + threadIdx.x;
    if (idx >= B_ * S_ * D_) return;
    int r = idx % (S_ * D_);
    int s = r / D_, d = r % D_;
    if (s == 0) tok[idx] = cls[d] + pos[d];
    else tok[idx] += pos[r];
}

// ---------------- layernorm (one block per row of 768) ----------------
__global__ __launch_bounds__(256) void ln_kernel(const float* __restrict__ x, float* __restrict__ y,
                                                 const float* __restrict__ g, const float* __restrict__ b) {
    int row = blockIdx.x;
    const float* xr = x + (long long)row * D_;
    float* yr = y + (long long)row * D_;
    int tid = threadIdx.x;
    float v[3];
    float s = 0.f;
#pragma unroll
    for (int u = 0; u < 3; ++u) { v[u] = xr[tid + 256 * u]; s += v[u]; }
    __shared__ float red[256];
    red[tid] = s; __syncthreads();
    for (int off = 128; off > 0; off >>= 1) { if (tid < off) red[tid] += red[tid + off]; __syncthreads(); }
    float mu = red[0] * (1.0f / D_);
    __syncthreads();
    float s2 = 0.f;
#pragma unroll
    for (int u = 0; u < 3; ++u) { float d = v[u] - mu; s2 += d * d; }
    red[tid] = s2; __syncthreads();
    for (int off = 128; off > 0; off >>= 1) { if (tid < off) red[tid] += red[tid + off]; __syncthreads(); }
    float rstd = rsqrtf(red[0] * (1.0f / D_) + 1e-5f);
#pragma unroll
    for (int u = 0; u < 3; ++u) {
        int d = tid + 256 * u;
        yr[d] = (v[u] - mu) * rstd * g[d] + b[d];
    }
}

// ---------------- attention softmax: one wave per row of S_ ----------------
__global__ __launch_bounds__(64) void att_softmax_kernel(float* __restrict__ att, float scale) {
    long long row = blockIdx.x;
    float* p = att + row * S_;
    int tid = threadIdx.x;
    float v[4];
    float mx = -1e30f;
#pragma unroll
    for (int u = 0; u < 4; ++u) {
        int t = tid + 64 * u;
        v[u] = (t < S_) ? p[t] * scale : -1e30f;
        mx = fmaxf(mx, v[u]);
    }
    for (int off = 32; off > 0; off >>= 1) mx = fmaxf(mx, __shfl_xor(mx, off));
    float sum = 0.f;
#pragma unroll
    for (int u = 0; u < 4; ++u) { v[u] = expf(v[u] - mx); sum += v[u]; }
    for (int off = 32; off > 0; off >>= 1) sum += __shfl_xor(sum, off);
    float inv = 1.0f / sum;
#pragma unroll
    for (int u = 0; u < 4; ++u) {
        int t = tid + 64 * u;
        if (t < S_) p[t] = v[u] * inv;
    }
}

// ---------------- head softmax: one block per row of 1000 ----------------
__global__ __launch_bounds__(256) void head_softmax_kernel(const float* __restrict__ logits,
                                                           float* __restrict__ out) {
    int n = blockIdx.x;
    const float* p = logits + (long long)n * OUT_;
    int tid = threadIdx.x;
    float v[4];
    float mx = -1e30f;
#pragma unroll
    for (int u = 0; u < 4; ++u) {
        int idx = tid + 256 * u;
        v[u] = (idx < OUT_) ? p[idx] : -1e30f;
        mx = fmaxf(mx, v[u]);
    }
    __shared__ float red[256];
    red[tid] = mx; __syncthreads();
    for (int off = 128; off > 0; off >>= 1) { if (tid < off) red[tid] = fmaxf(red[tid], red[tid + off]); __syncthreads(); }
    mx = red[0];
    __syncthreads();
    float sum = 0.f;
#pragma unroll
    for (int u = 0; u < 4; ++u) { v[u] = expf(v[u] - mx); sum += v[u]; }
    red[tid] = sum; __syncthreads();
    for (int off = 128; off > 0; off >>= 1) { if (tid < off) red[tid] += red[tid + off]; __syncthreads(); }
    float inv = 1.0f / red[0];
#pragma unroll
    for (int u = 0; u < 4; ++u) {
        int idx = tid + 256 * u;
        if (idx < OUT_) out[(long long)n * OUT_ + idx] = v[u] * inv;
    }
}

// ---------------- host helpers ----------------
struct Off { int div; long long so, si; };

static inline void launch_gemm(hipStream_t st, const float* A, const float* Bm, const float* bias,
                               float* C, int M, int N, int K, int lda, int ldb, int ldc,
                               int transB, int act, int accum, int batch,
                               Off a, Off b, Off c, Off bb) {
    dim3 grid((N + BN - 1) / BN, (M + BM - 1) / BM, batch);
    gemm_kernel<<<grid, dim3(256), 0, st>>>(A, Bm, bias, C, M, N, K, lda, ldb, ldc,
                                            transB, act, accum,
                                            a.div, a.so, a.si, b.div, b.so, b.si,
                                            c.div, c.so, c.si, bb.div, bb.so, bb.si);
}

extern "C" void kernel_launch(void* const* d_in, const int* in_sizes, int n_in,
                              void* d_out, int out_size, void* d_ws, size_t ws_size,
                              hipStream_t stream) {
    (void)in_sizes; (void)n_in; (void)out_size; (void)ws_size;
    const float* x        = (const float*)d_in[0];
    const float* w_embed  = (const float*)d_in[1];
    const float* b_embed  = (const float*)d_in[2];
    const float* cls_tok  = (const float*)d_in[3];
    const float* ln1_g    = (const float*)d_in[4];
    const float* ln1_b    = (const float*)d_in[5];
    const float* wq       = (const float*)d_in[6];
    const float* bq       = (const float*)d_in[7];
    const float* wk       = (const float*)d_in[8];
    const float* bk       = (const float*)d_in[9];
    const float* wv       = (const float*)d_in[10];
    const float* bv       = (const float*)d_in[11];
    const float* ln2_g    = (const float*)d_in[12];
    const float* ln2_b    = (const float*)d_in[13];
    const float* w1       = (const float*)d_in[14];
    const float* b1       = (const float*)d_in[15];
    const float* w2       = (const float*)d_in[16];
    const float* b2       = (const float*)d_in[17];
    const float* w_head   = (const float*)d_in[18];
    const float* b_head   = (const float*)d_in[19];
    float* out = (float*)d_out;
    float* ws  = (float*)d_ws;

    const long long TOKSZ = (long long)B_ * S_ * D_;          // 4,841,472
    const long long BIGSZ = (long long)B_ * S_ * MLP_;        // 19,365,888 (>= att 14,902,656)

    long long off = 0;
    float* pos    = ws + off; off += (long long)S_ * D_;
    float* tok    = ws + off; off += TOKSZ;
    float* hbuf   = ws + off; off += TOKSZ;
    float* qbuf   = ws + off; off += TOKSZ;   // also holds patches pre-loop
    float* kbuf   = ws + off; off += TOKSZ;
    float* vbuf   = ws + off; off += TOKSZ;
    float* big    = ws + off; off += BIGSZ;   // att scores / mlp hidden
    float* logits = ws + off; off += (long long)B_ * OUT_;
    float* patches = qbuf;

    const Off Z0 = {1, 0, 0};

    // pos emb
    posemb_kernel<<<(S_ * D_ + 255) / 256, 256, 0, stream>>>(pos);
    // patchify
    patchify_kernel<<<(B_ * NP_ * NP_ * 768 + 255) / 256, 256, 0, stream>>>(x, patches);
    // embed GEMM: batch=B, M=196, K=768, N=768 ; C = tok rows 1..196 per image
    launch_gemm(stream, patches, w_embed, b_embed, tok + D_,
                NP_ * NP_, D_, 768, 768, D_, D_, 0, 0, 0, B_,
                Off{1, (long long)NP_ * NP_ * 768, 0}, Z0,
                Off{1, (long long)S_ * D_, 0}, Z0);
    // cls + pos
    addpos_kernel<<<((int)TOKSZ + 255) / 256, 256, 0, stream>>>(tok, pos, cls_tok);

    const int NB = B_ * NH_;  // 384
    const float scale = 0.125f;  // 1/sqrt(64)

    for (int l = 0; l < L_; ++l) {
        // LN1
        ln_kernel<<<B_ * S_, 256, 0, stream>>>(tok, hbuf, ln1_g + l * D_, ln1_b + l * D_);
        // QKV: batch over (n,h); A = hbuf col-offset h*64 ; B = w[l,h] 64x64 ; C = [B,NH,S,DH]
        Off aOff = {NH_, (long long)S_ * D_, DH_};
        Off wOffQ = {NH_, 0, (long long)DH_ * DH_};
        Off cOff = {1, (long long)S_ * DH_, 0};
        Off bOff = {NH_, 0, DH_};
        launch_gemm(stream, hbuf, wq + (long long)l * NH_ * DH_ * DH_, bq + (long long)l * NH_ * DH_,
                    qbuf, S_, DH_, DH_, D_, DH_, DH_, 0, 0, 0, NB, aOff, wOffQ, cOff, bOff);
        launch_gemm(stream, hbuf, wk + (long long)l * NH_ * DH_ * DH_, bk + (long long)l * NH_ * DH_,
                    kbuf, S_, DH_, DH_, D_, DH_, DH_, 0, 0, 0, NB, aOff, wOffQ, cOff, bOff);
        launch_gemm(stream, hbuf, wv + (long long)l * NH_ * DH_ * DH_, bv + (long long)l * NH_ * DH_,
                    vbuf, S_, DH_, DH_, D_, DH_, DH_, 0, 0, 0, NB, aOff, wOffQ, cOff, bOff);
        // scores = q @ k^T : batch (n,h), M=N=S, K=64
        launch_gemm(stream, qbuf, kbuf, nullptr, big,
                    S_, S_, DH_, DH_, DH_, S_, 1, 0, 0, NB,
                    Off{1, (long long)S_ * DH_, 0}, Off{1, (long long)S_ * DH_, 0},
                    Off{1, (long long)S_ * S_, 0}, Z0);
        // softmax rows
        att_softmax_kernel<<<NB * S_, 64, 0, stream>>>(big, scale);
        // O = att @ v, accumulated into tok (residual)
        launch_gemm(stream, big, vbuf, nullptr, tok,
                    S_, DH_, S_, S_, DH_, D_, 0, 0, 1, NB,
                    Off{1, (long long)S_ * S_, 0}, Off{1, (long long)S_ * DH_, 0},
                    Off{NH_, (long long)S_ * D_, DH_}, Z0);
        // LN2
        ln_kernel<<<B_ * S_, 256, 0, stream>>>(tok, hbuf, ln2_g + l * D_, ln2_b + l * D_);
        // MLP1 + GELU
        launch_gemm(stream, hbuf, w1 + (long long)l * D_ * MLP_, b1 + (long long)l * MLP_, big,
                    B_ * S_, MLP_, D_, D_, MLP_, MLP_, 0, 1, 0, 1, Z0, Z0, Z0, Z0);
        // MLP2 + residual
        launch_gemm(stream, big, w2 + (long long)l * MLP_ * D_, b2 + (long long)l * D_, tok,
                    B_ * S_, D_, MLP_, MLP_, D_, D_, 0, 0, 1, 1, Z0, Z0, Z0, Z0);
    }

    // head: logits = tok[:,0,:] @ w_head + b_head
    launch_gemm(stream, tok, w_head, b_head, logits,
                B_, OUT_, D_, S_ * D_, OUT_, OUT_, 0, 0, 0, 1, Z0, Z0, Z0, Z0);
    head_softmax_kernel<<<B_, 256, 0, stream>>>(logits, out);
}

// Round 2
// 12202.970 us; speedup vs baseline: 1.6905x; 1.6905x over previous
//
#include <hip/hip_runtime.h>
#include <math.h>

// ---------------- dims ----------------
#define B_ 32
#define C_ 3
#define HW_ 224
#define NP_ 14
#define PS_ 16
#define S_ 197        // NP*NP + 1
#define D_ 768
#define NH_ 12
#define DH_ 64
#define L_ 12
#define MLP_ 3072
#define OUT_ 1000

#define BM 64
#define BN 64
#define BK 16

typedef unsigned short u16;
typedef unsigned int u32;
typedef __attribute__((ext_vector_type(8))) short short8_t;
typedef __attribute__((ext_vector_type(4))) float f32x4;
typedef const __attribute__((address_space(1))) u16 gq_t;
typedef __attribute__((address_space(3))) u16 lq_t;

// ---------------- bf16 helpers ----------------
__device__ __forceinline__ u16 f2bf(float x) {
    union { float f; u32 u; } a; a.f = x;
    u32 r = (a.u + 0x7fffu + ((a.u >> 16) & 1u)) >> 16;   // RNE
    return (u16)r;
}
__device__ __forceinline__ float bf2f(u16 h) {
    union { u32 u; float f; } a; a.u = ((u32)h) << 16; return a.f;
}

// ================= bf16x3 split MFMA GEMM =================
// C = A @ B^T(stored [N,K]) using hi/lo bf16 decomposition of fp32 inputs.
// 3 MFMAs per product: hi*hi + hi*lo + lo*hi  (~2^-16 relative error).
// mode 0: C[orow*ldc+col] = acc + bias (+C_old if accum); orow=remap? m+m/196+1 : m
// mode 1: gelu(acc+bias) -> write bf16 hi/lo pair (Ohi/Olo, ld=N)
__global__ __launch_bounds__(256) void mfma_gemm_kernel(
    const u16* __restrict__ Ahi, const u16* __restrict__ Alo,
    const u16* __restrict__ Bhi, const u16* __restrict__ Blo,
    const float* __restrict__ bias, float* __restrict__ C,
    u16* __restrict__ Ohi, u16* __restrict__ Olo,
    int M, int N, int K, int ldc, int mode, int accum, int remap)
{
    // chunk-major LDS: [mat][k-octet][row][8 bf16] -> conflict-free b128 reads,
    // and global_load_lds lands lane L at row h*64+L (contiguous 16B/lane).
    __shared__ u16 lds[4][4][128][8];   // 32 KB

    int tid = threadIdx.x;
    int lane = tid & 63;
    int w = tid >> 6;                  // wave id 0..3
    int wm = (w >> 1) * 64, wn = (w & 1) * 64;
    int m0 = blockIdx.y * 128, n0 = blockIdx.x * 128;
    int lm = lane & 15, qd = lane >> 4;

    const u16* src = (w == 0) ? Ahi : (w == 1) ? Alo : (w == 2) ? Bhi : Blo;
    int base = (w < 2) ? m0 : n0;
    int rmax = ((w < 2) ? M : N) - 1;

    f32x4 acc[4][4];
#pragma unroll
    for (int i = 0; i < 4; ++i)
#pragma unroll
        for (int j = 0; j < 4; ++j)
            acc[i][j] = (f32x4){0.f, 0.f, 0.f, 0.f};

    for (int k0 = 0; k0 < K; k0 += 32) {
        // ---- stage: wave w loads matrix w (8 x global_load_lds, 16B/lane) ----
        int r0 = base + lane;
#pragma unroll
        for (int q = 0; q < 4; ++q) {
#pragma unroll
            for (int h = 0; h < 2; ++h) {
                int rr = r0 + h * 64;
                rr = rr > rmax ? rmax : rr;
                const u16* gp = src + (long long)rr * K + (k0 + q * 8);
                u16* lp = &lds[w][q][h * 64][0];
                __builtin_amdgcn_global_load_lds((gq_t*)gp, (lq_t*)lp, 16, 0, 0);
            }
        }
        __syncthreads();

        short8_t ah[4], al[4], bh[4], bl[4];
#pragma unroll
        for (int i = 0; i < 4; ++i) {
            ah[i] = *(const short8_t*)&lds[0][qd][wm + i * 16 + lm][0];
            al[i] = *(const short8_t*)&lds[1][qd][wm + i * 16 + lm][0];
            bh[i] = *(const short8_t*)&lds[2][qd][wn + i * 16 + lm][0];
            bl[i] = *(const short8_t*)&lds[3][qd][wn + i * 16 + lm][0];
        }
#pragma unroll
        for (int i = 0; i < 4; ++i)
#pragma unroll
            for (int j = 0; j < 4; ++j) {
                acc[i][j] = __builtin_amdgcn_mfma_f32_16x16x32_bf16(ah[i], bh[j], acc[i][j], 0, 0, 0);
                acc[i][j] = __builtin_amdgcn_mfma_f32_16x16x32_bf16(ah[i], bl[j], acc[i][j], 0, 0, 0);
                acc[i][j] = __builtin_amdgcn_mfma_f32_16x16x32_bf16(al[i], bh[j], acc[i][j], 0, 0, 0);
            }
        __syncthreads();
    }

    // ---- epilogue: C/D layout col=lane&15, row=quad*4+reg ----
#pragma unroll
    for (int j = 0; j < 4; ++j) {
        int col = n0 + wn + j * 16 + lm;
        float bv = bias[col];
#pragma unroll
        for (int i = 0; i < 4; ++i) {
#pragma unroll
            for (int r = 0; r < 4; ++r) {
                int grow = m0 + wm + i * 16 + qd * 4 + r;
                if (grow >= M) continue;
                float v = acc[i][j][r] + bv;
                if (mode == 1) {
                    v = 0.5f * v * (1.0f + erff(v * 0.70710678118654752f));
                    u16 h = f2bf(v);
                    long long idx = (long long)grow * ldc + col;
                    Ohi[idx] = h;
                    Olo[idx] = f2bf(v - bf2f(h));
                } else {
                    int orow = remap ? (grow + grow / 196 + 1) : grow;
                    long long idx = (long long)orow * ldc + col;
                    if (accum) v += C[idx];
                    C[idx] = v;
                }
            }
        }
    }
}

// ---------------- transpose + hi/lo split of fp32 weights ----------------
// in:  W [K][N] fp32 row-major;  out: Thi/Tlo [N][K] bf16
__global__ __launch_bounds__(256) void tconv_kernel(const float* __restrict__ W,
                                                    u16* __restrict__ Thi, u16* __restrict__ Tlo,
                                                    int K, int N)
{
    __shared__ float t[32][33];
    int n0 = blockIdx.x * 32, k0 = blockIdx.y * 32;
    int tc = threadIdx.x & 31, tr = threadIdx.x >> 5;   // tr in 0..7
#pragma unroll
    for (int u = 0; u < 4; ++u) {
        int kk = tr + u * 8;
        t[kk][tc] = W[(long long)(k0 + kk) * N + n0 + tc];
    }
    __syncthreads();
#pragma unroll
    for (int u = 0; u < 4; ++u) {
        int nn = tr + u * 8;
        float v = t[tc][nn];
        u16 h = f2bf(v);
        long long idx = (long long)(n0 + nn) * K + k0 + tc;
        Thi[idx] = h;
        Tlo[idx] = f2bf(v - bf2f(h));
    }
}

// ================= fp32 generic batched GEMM (attention path) =================
__global__ __launch_bounds__(256) void gemm_kernel(
    const float* __restrict__ A, const float* __restrict__ Bm,
    const float* __restrict__ bias, float* __restrict__ C,
    int M, int N, int K, int lda, int ldb, int ldc,
    int transB, int act, int accum,
    int divA, long long sAo, long long sAi,
    int divB, long long sBo, long long sBi,
    int divC, long long sCo, long long sCi,
    int divBias, long long sBiaso, long long sBiasi)
{
    int z = blockIdx.z;
    const float* Ab = A + (long long)(z / divA) * sAo + (long long)(z % divA) * sAi;
    const float* Bb = Bm + (long long)(z / divB) * sBo + (long long)(z % divB) * sBi;
    float* Cb = C + (long long)(z / divC) * sCo + (long long)(z % divC) * sCi;
    const float* biasb = bias ? (bias + (long long)(z / divBias) * sBiaso + (long long)(z % divBias) * sBiasi)
                              : nullptr;

    __shared__ float As[BK][BM + 4];
    __shared__ float Bs[BK][BN + 4];

    int tid = threadIdx.x;
    int tx = tid & 15, ty = tid >> 4;
    int m0 = blockIdx.y * BM, n0 = blockIdx.x * BN;

    float acc[4][4] = {};

    for (int k0 = 0; k0 < K; k0 += BK) {
        {
            int row = tid >> 2;
            int c4 = (tid & 3) * 4;
            int gm = m0 + row;
#pragma unroll
            for (int u = 0; u < 4; ++u) {
                int gk = k0 + c4 + u;
                float v = 0.f;
                if (gm < M && gk < K) v = Ab[(long long)gm * lda + gk];
                As[c4 + u][row] = v;
            }
        }
        if (!transB) {
            int row = tid >> 4;
            int c4 = (tid & 15) * 4;
            int gk = k0 + row;
#pragma unroll
            for (int u = 0; u < 4; ++u) {
                int gn = n0 + c4 + u;
                float v = 0.f;
                if (gk < K && gn < N) v = Bb[(long long)gk * ldb + gn];
                Bs[row][c4 + u] = v;
            }
        } else {
            int row = tid >> 2;
            int c4 = (tid & 3) * 4;
            int gn = n0 + row;
#pragma unroll
            for (int u = 0; u < 4; ++u) {
                int gk = k0 + c4 + u;
                float v = 0.f;
                if (gn < N && gk < K) v = Bb[(long long)gn * ldb + gk];
                Bs[c4 + u][row] = v;
            }
        }
        __syncthreads();
#pragma unroll
        for (int kk = 0; kk < BK; ++kk) {
            float a[4], b[4];
#pragma unroll
            for (int i = 0; i < 4; ++i) a[i] = As[kk][ty * 4 + i];
#pragma unroll
            for (int j = 0; j < 4; ++j) b[j] = Bs[kk][tx * 4 + j];
#pragma unroll
            for (int i = 0; i < 4; ++i)
#pragma unroll
                for (int j = 0; j < 4; ++j)
                    acc[i][j] += a[i] * b[j];
        }
        __syncthreads();
    }

#pragma unroll
    for (int i = 0; i < 4; ++i) {
        int gm = m0 + ty * 4 + i;
        if (gm >= M) continue;
#pragma unroll
        for (int j = 0; j < 4; ++j) {
            int gn = n0 + tx * 4 + j;
            if (gn >= N) continue;
            float v = acc[i][j];
            if (biasb) v += biasb[gn];
            if (act == 1) v = 0.5f * v * (1.0f + erff(v * 0.70710678118654752f));
            long long idx = (long long)gm * ldc + gn;
            if (accum) v += Cb[idx];
            Cb[idx] = v;
        }
    }
}

// ---------------- positional embedding ----------------
__global__ void posemb_kernel(float* __restrict__ pos) {
    int idx = blockIdx.x * 256 + threadIdx.x;
    if (idx >= S_ * D_) return;
    int s = idx / D_, d = idx % D_;
    float jj = (float)(d & ~1);
    float freq = powf(10000.0f, jj / (float)D_);
    float arg = (float)s / freq;
    pos[idx] = (d & 1) ? cosf(arg) : sinf(arg);
}

// ---------------- patchify (writes bf16 hi/lo) ----------------
__global__ void patchify_split_kernel(const float* __restrict__ x,
                                      u16* __restrict__ phi, u16* __restrict__ plo) {
    int idx = blockIdx.x * 256 + threadIdx.x;
    if (idx >= B_ * NP_ * NP_ * 768) return;
    int k = idx % 768;
    int p = (idx / 768) % (NP_ * NP_);
    int n = idx / (768 * NP_ * NP_);
    int c = k >> 8;
    int rem = k & 255;
    int a = rem >> 4;
    int b = rem & 15;
    int i = p / NP_, j = p % NP_;
    float v = x[(((long long)n * C_ + c) * HW_ + (i * PS_ + a)) * HW_ + (j * PS_ + b)];
    u16 h = f2bf(v);
    phi[idx] = h;
    plo[idx] = f2bf(v - bf2f(h));
}

// ---------------- cls token + pos emb ----------------
__global__ void addpos_kernel(float* __restrict__ tok, const float* __restrict__ pos,
                              const float* __restrict__ cls) {
    int idx = blockIdx.x * 256 + threadIdx.x;
    if (idx >= B_ * S_ * D_) return;
    int r = idx % (S_ * D_);
    int s = r / D_, d = r % D_;
    if (s == 0) tok[idx] = cls[d] + pos[d];
    else tok[idx] += pos[r];
}

// ---------------- layernorm fp32 out (LN1) ----------------
__global__ __launch_bounds__(256) void ln_kernel(const float* __restrict__ x, float* __restrict__ y,
                                                 const float* __restrict__ g, const float* __restrict__ b) {
    int row = blockIdx.x;
    const float* xr = x + (long long)row * D_;
    float* yr = y + (long long)row * D_;
    int tid = threadIdx.x;
    float v[3];
    float s = 0.f;
#pragma unroll
    for (int u = 0; u < 3; ++u) { v[u] = xr[tid + 256 * u]; s += v[u]; }
    __shared__ float red[256];
    red[tid] = s; __syncthreads();
    for (int off = 128; off > 0; off >>= 1) { if (tid < off) red[tid] += red[tid + off]; __syncthreads(); }
    float mu = red[0] * (1.0f / D_);
    __syncthreads();
    float s2 = 0.f;
#pragma unroll
    for (int u = 0; u < 3; ++u) { float d = v[u] - mu; s2 += d * d; }
    red[tid] = s2; __syncthreads();
    for (int off = 128; off > 0; off >>= 1) { if (tid < off) red[tid] += red[tid + off]; __syncthreads(); }
    float rstd = rsqrtf(red[0] * (1.0f / D_) + 1e-5f);
#pragma unroll
    for (int u = 0; u < 3; ++u) {
        int d = tid + 256 * u;
        yr[d] = (v[u] - mu) * rstd * g[d] + b[d];
    }
}

// ---------------- layernorm bf16 hi/lo out (LN2) ----------------
__global__ __launch_bounds__(256) void ln_split_kernel(const float* __restrict__ x,
                                                       u16* __restrict__ yhi, u16* __restrict__ ylo,
                                                       const float* __restrict__ g, const float* __restrict__ b) {
    int row = blockIdx.x;
    const float* xr = x + (long long)row * D_;
    u16* yh = yhi + (long long)row * D_;
    u16* yl = ylo + (long long)row * D_;
    int tid = threadIdx.x;
    float v[3];
    float s = 0.f;
#pragma unroll
    for (int u = 0; u < 3; ++u) { v[u] = xr[tid + 256 * u]; s += v[u]; }
    __shared__ float red[256];
    red[tid] = s; __syncthreads();
    for (int off = 128; off > 0; off >>= 1) { if (tid < off) red[tid] += red[tid + off]; __syncthreads(); }
    float mu = red[0] * (1.0f / D_);
    __syncthreads();
    float s2 = 0.f;
#pragma unroll
    for (int u = 0; u < 3; ++u) { float d = v[u] - mu; s2 += d * d; }
    red[tid] = s2; __syncthreads();
    for (int off = 128; off > 0; off >>= 1) { if (tid < off) red[tid] += red[tid + off]; __syncthreads(); }
    float rstd = rsqrtf(red[0] * (1.0f / D_) + 1e-5f);
#pragma unroll
    for (int u = 0; u < 3; ++u) {
        int d = tid + 256 * u;
        float yv = (v[u] - mu) * rstd * g[d] + b[d];
        u16 h = f2bf(yv);
        yh[d] = h;
        yl[d] = f2bf(yv - bf2f(h));
    }
}

// ---------------- attention softmax: one wave per row of S_ ----------------
__global__ __launch_bounds__(64) void att_softmax_kernel(float* __restrict__ att, float scale) {
    long long row = blockIdx.x;
    float* p = att + row * S_;
    int tid = threadIdx.x;
    float v[4];
    float mx = -1e30f;
#pragma unroll
    for (int u = 0; u < 4; ++u) {
        int t = tid + 64 * u;
        v[u] = (t < S_) ? p[t] * scale : -1e30f;
        mx = fmaxf(mx, v[u]);
    }
    for (int off = 32; off > 0; off >>= 1) mx = fmaxf(mx, __shfl_xor(mx, off));
    float sum = 0.f;
#pragma unroll
    for (int u = 0; u < 4; ++u) { v[u] = expf(v[u] - mx); sum += v[u]; }
    for (int off = 32; off > 0; off >>= 1) sum += __shfl_xor(sum, off);
    float inv = 1.0f / sum;
#pragma unroll
    for (int u = 0; u < 4; ++u) {
        int t = tid + 64 * u;
        if (t < S_) p[t] = v[u] * inv;
    }
}

// ---------------- head softmax ----------------
__global__ __launch_bounds__(256) void head_softmax_kernel(const float* __restrict__ logits,
                                                           float* __restrict__ out) {
    int n = blockIdx.x;
    const float* p = logits + (long long)n * OUT_;
    int tid = threadIdx.x;
    float v[4];
    float mx = -1e30f;
#pragma unroll
    for (int u = 0; u < 4; ++u) {
        int idx = tid + 256 * u;
        v[u] = (idx < OUT_) ? p[idx] : -1e30f;
        mx = fmaxf(mx, v[u]);
    }
    __shared__ float red[256];
    red[tid] = mx; __syncthreads();
    for (int off = 128; off > 0; off >>= 1) { if (tid < off) red[tid] = fmaxf(red[tid], red[tid + off]); __syncthreads(); }
    mx = red[0];
    __syncthreads();
    float sum = 0.f;
#pragma unroll
    for (int u = 0; u < 4; ++u) { v[u] = expf(v[u] - mx); sum += v[u]; }
    red[tid] = sum; __syncthreads();
    for (int off = 128; off > 0; off >>= 1) { if (tid < off) red[tid] += red[tid + off]; __syncthreads(); }
    float inv = 1.0f / red[0];
#pragma unroll
    for (int u = 0; u < 4; ++u) {
        int idx = tid + 256 * u;
        if (idx < OUT_) out[(long long)n * OUT_ + idx] = v[u] * inv;
    }
}

// ---------------- host helpers ----------------
struct Off { int div; long long so, si; };

static inline void launch_gemm(hipStream_t st, const float* A, const float* Bm, const float* bias,
                               float* C, int M, int N, int K, int lda, int ldb, int ldc,
                               int transB, int act, int accum, int batch,
                               Off a, Off b, Off c, Off bb) {
    dim3 grid((N + BN - 1) / BN, (M + BM - 1) / BM, batch);
    gemm_kernel<<<grid, dim3(256), 0, st>>>(A, Bm, bias, C, M, N, K, lda, ldb, ldc,
                                            transB, act, accum,
                                            a.div, a.so, a.si, b.div, b.so, b.si,
                                            c.div, c.so, c.si, bb.div, bb.so, bb.si);
}

static inline void launch_mfma(hipStream_t st,
                               const u16* Ahi, const u16* Alo, const u16* Bhi, const u16* Blo,
                               const float* bias, float* C, u16* Ohi, u16* Olo,
                               int M, int N, int K, int ldc, int mode, int accum, int remap) {
    dim3 grid(N / 128, (M + 127) / 128, 1);
    mfma_gemm_kernel<<<grid, dim3(256), 0, st>>>(Ahi, Alo, Bhi, Blo, bias, C, Ohi, Olo,
                                                 M, N, K, ldc, mode, accum, remap);
}

extern "C" void kernel_launch(void* const* d_in, const int* in_sizes, int n_in,
                              void* d_out, int out_size, void* d_ws, size_t ws_size,
                              hipStream_t stream) {
    (void)in_sizes; (void)n_in; (void)out_size; (void)ws_size;
    const float* x        = (const float*)d_in[0];
    const float* w_embed  = (const float*)d_in[1];
    const float* b_embed  = (const float*)d_in[2];
    const float* cls_tok  = (const float*)d_in[3];
    const float* ln1_g    = (const float*)d_in[4];
    const float* ln1_b    = (const float*)d_in[5];
    const float* wq       = (const float*)d_in[6];
    const float* bq       = (const float*)d_in[7];
    const float* wk       = (const float*)d_in[8];
    const float* bk       = (const float*)d_in[9];
    const float* wv       = (const float*)d_in[10];
    const float* bv       = (const float*)d_in[11];
    const float* ln2_g    = (const float*)d_in[12];
    const float* ln2_b    = (const float*)d_in[13];
    const float* w1       = (const float*)d_in[14];
    const float* b1       = (const float*)d_in[15];
    const float* w2       = (const float*)d_in[16];
    const float* b2       = (const float*)d_in[17];
    const float* w_head   = (const float*)d_in[18];
    const float* b_head   = (const float*)d_in[19];
    float* out = (float*)d_out;
    char* wsb  = (char*)d_ws;

    const long long TOKSZ = (long long)B_ * S_ * D_;          // 4,841,472 tokens*D
    const int M_TOK = B_ * S_;                                 // 6304
    const int M_PAT = B_ * NP_ * NP_;                          // 6272

    // ---- workspace carve (bytes, 256B aligned) ----
    auto alloc = [&](long long bytes) {
        char* p = wsb;
        wsb += (bytes + 255) & ~255LL;
        return p;
    };
    float* pos    = (float*)alloc((long long)S_ * D_ * 4);
    float* tok    = (float*)alloc(TOKSZ * 4);
    float* hbuf   = (float*)alloc(TOKSZ * 4);                  // LN1 out (fp32)
    float* qbuf   = (float*)alloc(TOKSZ * 4);
    float* kbuf   = (float*)alloc(TOKSZ * 4);
    float* vbuf   = (float*)alloc(TOKSZ * 4);
    u16*   h_hi   = (u16*)alloc(TOKSZ * 2);                    // LN2 out hi
    u16*   h_lo   = (u16*)alloc(TOKSZ * 2);
    u16*   w1t_hi = (u16*)alloc((long long)MLP_ * D_ * 2);     // also wet_hi pre-loop
    u16*   w1t_lo = (u16*)alloc((long long)MLP_ * D_ * 2);     // also wet_lo pre-loop
    u16*   w2t_hi = (u16*)alloc((long long)D_ * MLP_ * 2);
    u16*   w2t_lo = (u16*)alloc((long long)D_ * MLP_ * 2);
    // big region: max(att scores fp32 59.6MB, gelu hi+lo 77.5MB, patches hi+lo 19.3MB)
    char* bigreg  = alloc((long long)M_TOK * MLP_ * 2 * 2);
    float* att    = (float*)bigreg;                            // [B*NH, S, S]
    u16*   g_hi   = (u16*)bigreg;                              // [M_TOK, MLP]
    u16*   g_lo   = g_hi + (long long)M_TOK * MLP_;
    u16*   p_hi   = (u16*)bigreg;                              // [M_PAT, 768] pre-loop
    u16*   p_lo   = p_hi + (long long)M_PAT * 768;
    float* logits = (float*)alloc((long long)B_ * OUT_ * 4);

    const Off Z0 = {1, 0, 0};

    // ---- embed path ----
    posemb_kernel<<<(S_ * D_ + 255) / 256, 256, 0, stream>>>(pos);
    patchify_split_kernel<<<(M_PAT * 768 + 255) / 256, 256, 0, stream>>>(x, p_hi, p_lo);
    // transpose+split w_embed [768,768] -> [768,768] (reuse w1t buffers)
    tconv_kernel<<<dim3(768 / 32, 768 / 32), 256, 0, stream>>>(w_embed, w1t_hi, w1t_lo, 768, 768);
    // tokens[:,1:,:] = patches @ w_embed + b_embed  (row remap m -> m + m/196 + 1)
    launch_mfma(stream, p_hi, p_lo, w1t_hi, w1t_lo, b_embed, tok, nullptr, nullptr,
                M_PAT, D_, 768, D_, 0, 0, 1);
    addpos_kernel<<<((int)TOKSZ + 255) / 256, 256, 0, stream>>>(tok, pos, cls_tok);

    const int NB = B_ * NH_;  // 384
    const float scale = 0.125f;

    for (int l = 0; l < L_; ++l) {
        // LN1 (fp32 out for fp32 attention path)
        ln_kernel<<<M_TOK, 256, 0, stream>>>(tok, hbuf, ln1_g + l * D_, ln1_b + l * D_);
        // QKV fp32 (batched per (n,h))
        Off aOff = {NH_, (long long)S_ * D_, DH_};
        Off wOffQ = {NH_, 0, (long long)DH_ * DH_};
        Off cOff = {1, (long long)S_ * DH_, 0};
        Off bOff = {NH_, 0, DH_};
        launch_gemm(stream, hbuf, wq + (long long)l * NH_ * DH_ * DH_, bq + (long long)l * NH_ * DH_,
                    qbuf, S_, DH_, DH_, D_, DH_, DH_, 0, 0, 0, NB, aOff, wOffQ, cOff, bOff);
        launch_gemm(stream, hbuf, wk + (long long)l * NH_ * DH_ * DH_, bk + (long long)l * NH_ * DH_,
                    kbuf, S_, DH_, DH_, D_, DH_, DH_, 0, 0, 0, NB, aOff, wOffQ, cOff, bOff);
        launch_gemm(stream, hbuf, wv + (long long)l * NH_ * DH_ * DH_, bv + (long long)l * NH_ * DH_,
                    vbuf, S_, DH_, DH_, D_, DH_, DH_, 0, 0, 0, NB, aOff, wOffQ, cOff, bOff);
        // scores = q @ k^T
        launch_gemm(stream, qbuf, kbuf, nullptr, att,
                    S_, S_, DH_, DH_, DH_, S_, 1, 0, 0, NB,
                    Off{1, (long long)S_ * DH_, 0}, Off{1, (long long)S_ * DH_, 0},
                    Off{1, (long long)S_ * S_, 0}, Z0);
        att_softmax_kernel<<<NB * S_, 64, 0, stream>>>(att, scale);
        // O = att @ v  (+residual into tok)
        launch_gemm(stream, att, vbuf, nullptr, tok,
                    S_, DH_, S_, S_, DH_, D_, 0, 0, 1, NB,
                    Off{1, (long long)S_ * S_, 0}, Off{1, (long long)S_ * DH_, 0},
                    Off{NH_, (long long)S_ * D_, DH_}, Z0);
        // LN2 -> bf16 hi/lo
        ln_split_kernel<<<M_TOK, 256, 0, stream>>>(tok, h_hi, h_lo, ln2_g + l * D_, ln2_b + l * D_);
        // weights -> transposed bf16 hi/lo
        tconv_kernel<<<dim3(MLP_ / 32, D_ / 32), 256, 0, stream>>>(
            w1 + (long long)l * D_ * MLP_, w1t_hi, w1t_lo, D_, MLP_);
        tconv_kernel<<<dim3(D_ / 32, MLP_ / 32), 256, 0, stream>>>(
            w2 + (long long)l * MLP_ * D_, w2t_hi, w2t_lo, MLP_, D_);
        // MLP1: gelu(h @ w1 + b1) -> g hi/lo (bf16)
        launch_mfma(stream, h_hi, h_lo, w1t_hi, w1t_lo, b1 + (long long)l * MLP_,
                    nullptr, g_hi, g_lo, M_TOK, MLP_, D_, MLP_, 1, 0, 0);
        // MLP2: tok += g @ w2 + b2
        launch_mfma(stream, g_hi, g_lo, w2t_hi, w2t_lo, b2 + (long long)l * D_,
                    tok, nullptr, nullptr, M_TOK, D_, MLP_, D_, 0, 1, 0);
    }

    // head (fp32, tiny)
    launch_gemm(stream, tok, w_head, b_head, logits,
                B_, OUT_, D_, S_ * D_, OUT_, OUT_, 0, 0, 0, 1, Z0, Z0, Z0, Z0);
    head_softmax_kernel<<<B_, 256, 0, stream>>>(logits, out);
}